// Round 1
// baseline (16837.976 us; speedup 1.0000x reference)
//
#include <hip/hip_runtime.h>

typedef unsigned short ushort_t;
typedef __attribute__((ext_vector_type(8))) __bf16 bf16x8;
typedef __attribute__((ext_vector_type(4))) float f32x4;
typedef __attribute__((ext_vector_type(4))) unsigned int u32x4;
typedef __attribute__((ext_vector_type(4))) unsigned short u16x4;
typedef __attribute__((ext_vector_type(4))) float fl4;

__device__ __forceinline__ ushort_t f2bf(float f) {
    unsigned u = __float_as_uint(f);
    u += 0x7FFFu + ((u >> 16) & 1u);
    return (ushort_t)(u >> 16);
}

__device__ __forceinline__ bf16x8 ld_bf8(const ushort_t* p) {
    return __builtin_bit_cast(bf16x8, *(const u32x4*)p);
}

// ---------------------------------------------------------------------------
// GEMM: C[M,N] = epilogue(A[M,K](bf16) @ W[N,K]^T(fp32->bf16) + bias)
// 128x128 block tile, 4 waves, each wave 64x64 via 4x4 of 16x16x32 MFMA.
// grid = (ceil(M/128), N/128)  -> consecutive blocks share W strip (L2 reuse)
// ---------------------------------------------------------------------------
template<int OBF, int ADD, int GELU>
__global__ __launch_bounds__(256)
void gemm_kernel(const ushort_t* __restrict__ A, const float* __restrict__ W,
                 const float* __restrict__ bias, void* __restrict__ Cv,
                 int M, int N, int K)
{
    __shared__ ushort_t As[128 * 40];   // stride 40 bf16: 16B-aligned rows, 2-way banks
    __shared__ ushort_t Ws[128 * 40];
    const int tid  = threadIdx.x;
    const int lane = tid & 63, wv = tid >> 6;
    const int quad = lane >> 4, l16 = lane & 15;
    const int m0 = blockIdx.x * 128, n0 = blockIdx.y * 128;
    const int wm = (wv >> 1) * 64, wn = (wv & 1) * 64;

    f32x4 acc[4][4];
#pragma unroll
    for (int i = 0; i < 4; ++i)
#pragma unroll
        for (int j = 0; j < 4; ++j) acc[i][j] = (f32x4){0.f, 0.f, 0.f, 0.f};

    const int ar = tid >> 2, ac = (tid & 3) * 8;   // A: 8 bf16 per chunk
    const int wr = tid >> 3, wc = (tid & 7) * 4;   // W: 4 fp32 per chunk

    for (int kt = 0; kt < K; kt += 32) {
#pragma unroll
        for (int i = 0; i < 2; ++i) {
            int r = ar + i * 64;
            u32x4 v = (u32x4){0, 0, 0, 0};
            int gm = m0 + r;
            if (gm < M) v = *(const u32x4*)(A + (size_t)gm * K + kt + ac);
            *(u32x4*)(As + r * 40 + ac) = v;
        }
#pragma unroll
        for (int i = 0; i < 4; ++i) {
            int r = wr + i * 32;
            fl4 f = *(const fl4*)(W + (size_t)(n0 + r) * K + kt + wc);
            u16x4 h;
            h.x = f2bf(f.x); h.y = f2bf(f.y); h.z = f2bf(f.z); h.w = f2bf(f.w);
            *(u16x4*)(Ws + r * 40 + wc) = h;
        }
        __syncthreads();
        bf16x8 af[4], bfr[4];
#pragma unroll
        for (int i = 0; i < 4; ++i) af[i]  = ld_bf8(As + (wm + i * 16 + l16) * 40 + quad * 8);
#pragma unroll
        for (int j = 0; j < 4; ++j) bfr[j] = ld_bf8(Ws + (wn + j * 16 + l16) * 40 + quad * 8);
#pragma unroll
        for (int i = 0; i < 4; ++i)
#pragma unroll
            for (int j = 0; j < 4; ++j)
                acc[i][j] = __builtin_amdgcn_mfma_f32_16x16x32_bf16(af[i], bfr[j], acc[i][j], 0, 0, 0);
        __syncthreads();
    }

    float* Cf = (float*)Cv;
    ushort_t* Ch = (ushort_t*)Cv;
#pragma unroll
    for (int j = 0; j < 4; ++j) {
        int n = n0 + wn + j * 16 + l16;
        float bv = bias[n];
#pragma unroll
        for (int i = 0; i < 4; ++i) {
            int mb = m0 + wm + i * 16 + quad * 4;
#pragma unroll
            for (int r = 0; r < 4; ++r) {
                int m = mb + r;
                if (m < M) {
                    float v = acc[i][j][r] + bv;
                    if (GELU) v = 0.5f * v * (1.f + erff(v * 0.70710678118654752f));
                    size_t off = (size_t)m * N + n;
                    if (OBF) {
                        Ch[off] = f2bf(v);
                    } else {
                        float o = v;
                        if (ADD) o += Cf[off];
                        Cf[off] = o;
                    }
                }
            }
        }
    }
}

// ---------------------------------------------------------------------------
// Attention: one block per (b, h, 64 q-rows). K staged in LDS -> S via MFMA in
// registers -> row softmax via shfl -> P(bf16) to LDS -> V restaged transposed
// over the K region -> PV via MFMA. Prefix K/V tokens appended past token 197.
// ---------------------------------------------------------------------------
__global__ __launch_bounds__(256)
void attn_kernel(const ushort_t* __restrict__ qkv, const ushort_t* __restrict__ pk,
                 const ushort_t* __restrict__ pv, int plen, int pbs,
                 ushort_t* __restrict__ out)
{
    __shared__ ushort_t KV[224 * 72];   // phase1: K rows stride 72; phase2: Vt rows stride 232
    __shared__ ushort_t Ps[64 * 232];   // 4 waves x 16 rows, stride 232
    const int tid  = threadIdx.x;
    const int lane = tid & 63, wv = tid >> 6;
    const int quad = lane >> 4, l16 = lane & 15;
    const int b = blockIdx.x / 12, h = blockIdx.x % 12;
    const int q0 = blockIdx.y * 64;
    const int Nk = 197 + plen;

    // stage K: [224 tok][64 hd] bf16, zero-padded
    for (int i = tid; i < 224 * 8; i += 256) {
        int tok = i >> 3, c = (i & 7) * 8;
        u32x4 v = (u32x4){0, 0, 0, 0};
        if (tok < 197)
            v = *(const u32x4*)(qkv + (size_t)(b * 197 + tok) * 2304 + 768 + h * 64 + c);
        else if (tok < Nk)
            v = *(const u32x4*)(pk + (size_t)(b * pbs + (tok - 197)) * 768 + h * 64 + c);
        *(u32x4*)(KV + tok * 72 + c) = v;
    }
    __syncthreads();

    // Q fragments (A-layout: m=lane&15, k=quad*8+j), direct from global
    bf16x8 qf0 = __builtin_bit_cast(bf16x8, (u32x4){0, 0, 0, 0});
    bf16x8 qf1 = qf0;
    int qrow = q0 + wv * 16 + l16;
    if (qrow < 197) {
        const ushort_t* qp = qkv + (size_t)(b * 197 + qrow) * 2304 + h * 64 + quad * 8;
        qf0 = ld_bf8(qp);
        qf1 = ld_bf8(qp + 32);
    }

    f32x4 sarr[14];
#pragma unroll
    for (int t = 0; t < 14; ++t) {
        f32x4 s = (f32x4){0.f, 0.f, 0.f, 0.f};
        bf16x8 k0 = ld_bf8(KV + (t * 16 + l16) * 72 + quad * 8);
        bf16x8 k1 = ld_bf8(KV + (t * 16 + l16) * 72 + 32 + quad * 8);
        s = __builtin_amdgcn_mfma_f32_16x16x32_bf16(qf0, k0, s, 0, 0, 0);
        s = __builtin_amdgcn_mfma_f32_16x16x32_bf16(qf1, k1, s, 0, 0, 0);
        if (t * 16 + l16 >= Nk) s = (f32x4){-1e30f, -1e30f, -1e30f, -1e30f};
        sarr[t] = s;
    }

    // row max over 16 lanes holding the row's 16-col tiles (C-layout: row=quad*4+r)
    float mx[4] = {-1e30f, -1e30f, -1e30f, -1e30f};
#pragma unroll
    for (int t = 0; t < 14; ++t)
#pragma unroll
        for (int r = 0; r < 4; ++r) mx[r] = fmaxf(mx[r], sarr[t][r]);
#pragma unroll
    for (int off = 8; off >= 1; off >>= 1)
#pragma unroll
        for (int r = 0; r < 4; ++r) mx[r] = fmaxf(mx[r], __shfl_xor(mx[r], off));

    float sm[4] = {0.f, 0.f, 0.f, 0.f};
#pragma unroll
    for (int t = 0; t < 14; ++t)
#pragma unroll
        for (int r = 0; r < 4; ++r) {
            float p = __expf((sarr[t][r] - mx[r]) * 0.125f);
            sm[r] += p;
            Ps[(wv * 16 + quad * 4 + r) * 232 + t * 16 + l16] = f2bf(p);
        }
#pragma unroll
    for (int off = 8; off >= 1; off >>= 1)
#pragma unroll
        for (int r = 0; r < 4; ++r) sm[r] += __shfl_xor(sm[r], off);
    float rs[4];
#pragma unroll
    for (int r = 0; r < 4; ++r) rs[r] = 1.f / sm[r];
    __syncthreads();   // all K reads + P writes done

    // restage V transposed: Vt[hd][tok], stride 232
    for (int i = tid; i < 224 * 8; i += 256) {
        int tok = i >> 3, c = (i & 7) * 8;
        u32x4 v = (u32x4){0, 0, 0, 0};
        if (tok < 197)
            v = *(const u32x4*)(qkv + (size_t)(b * 197 + tok) * 2304 + 1536 + h * 64 + c);
        else if (tok < Nk)
            v = *(const u32x4*)(pv + (size_t)(b * pbs + (tok - 197)) * 768 + h * 64 + c);
        ushort_t tmp[8];
        *(u32x4*)tmp = v;
#pragma unroll
        for (int jj = 0; jj < 8; ++jj) KV[(c + jj) * 232 + tok] = tmp[jj];
    }
    __syncthreads();

    f32x4 oc[4];
#pragma unroll
    for (int j = 0; j < 4; ++j) oc[j] = (f32x4){0.f, 0.f, 0.f, 0.f};
#pragma unroll
    for (int ks = 0; ks < 7; ++ks) {
        bf16x8 pf = ld_bf8(Ps + (wv * 16 + l16) * 232 + ks * 32 + quad * 8);
#pragma unroll
        for (int j = 0; j < 4; ++j) {
            bf16x8 vf = ld_bf8(KV + (j * 16 + l16) * 232 + ks * 32 + quad * 8);
            oc[j] = __builtin_amdgcn_mfma_f32_16x16x32_bf16(pf, vf, oc[j], 0, 0, 0);
        }
    }
#pragma unroll
    for (int j = 0; j < 4; ++j) {
        int hd = h * 64 + j * 16 + l16;
#pragma unroll
        for (int r = 0; r < 4; ++r) {
            int qr = q0 + wv * 16 + quad * 4 + r;
            if (qr < 197) out[(size_t)(b * 197 + qr) * 768 + hd] = f2bf(oc[j][r] * rs[r]);
        }
    }
}

// ---------------------------------------------------------------------------
// LayerNorm over D=768, one block per row. out = bf16
// ---------------------------------------------------------------------------
__global__ __launch_bounds__(256)
void ln_kernel(const float* __restrict__ x, const float* __restrict__ g,
               const float* __restrict__ bt, ushort_t* __restrict__ out)
{
    const int row = blockIdx.x, tid = threadIdx.x;
    const float* xr = x + (size_t)row * 768;
    float v0 = xr[tid], v1 = xr[tid + 256], v2 = xr[tid + 512];
    float s = v0 + v1 + v2;
    float s2 = v0 * v0 + v1 * v1 + v2 * v2;
#pragma unroll
    for (int off = 32; off >= 1; off >>= 1) {
        s  += __shfl_xor(s, off);
        s2 += __shfl_xor(s2, off);
    }
    __shared__ float red[8];
    if ((tid & 63) == 0) { red[tid >> 6] = s; red[(tid >> 6) + 4] = s2; }
    __syncthreads();
    float S  = red[0] + red[1] + red[2] + red[3];
    float S2 = red[4] + red[5] + red[6] + red[7];
    float mean = S * (1.f / 768.f);
    float var  = fmaxf(S2 * (1.f / 768.f) - mean * mean, 0.f);
    float rstd = rsqrtf(var + 1e-6f);
    size_t o = (size_t)row * 768;
    out[o + tid]       = f2bf((v0 - mean) * rstd * g[tid]       + bt[tid]);
    out[o + tid + 256] = f2bf((v1 - mean) * rstd * g[tid + 256] + bt[tid + 256]);
    out[o + tid + 512] = f2bf((v2 - mean) * rstd * g[tid + 512] + bt[tid + 512]);
}

// LN on cls rows only (row b -> x row b*197), fp32 output [64,768]
__global__ __launch_bounds__(256)
void ln_cls_kernel(const float* __restrict__ x, const float* __restrict__ g,
                   const float* __restrict__ bt, float* __restrict__ out)
{
    const int b = blockIdx.x, tid = threadIdx.x;
    const float* xr = x + (size_t)b * 197 * 768;
    float v0 = xr[tid], v1 = xr[tid + 256], v2 = xr[tid + 512];
    float s = v0 + v1 + v2;
    float s2 = v0 * v0 + v1 * v1 + v2 * v2;
#pragma unroll
    for (int off = 32; off >= 1; off >>= 1) {
        s  += __shfl_xor(s, off);
        s2 += __shfl_xor(s2, off);
    }
    __shared__ float red[8];
    if ((tid & 63) == 0) { red[tid >> 6] = s; red[(tid >> 6) + 4] = s2; }
    __syncthreads();
    float S  = red[0] + red[1] + red[2] + red[3];
    float S2 = red[4] + red[5] + red[6] + red[7];
    float mean = S * (1.f / 768.f);
    float var  = fmaxf(S2 * (1.f / 768.f) - mean * mean, 0.f);
    float rstd = rsqrtf(var + 1e-6f);
    out[b * 768 + tid]       = (v0 - mean) * rstd * g[tid]       + bt[tid];
    out[b * 768 + tid + 256] = (v1 - mean) * rstd * g[tid + 256] + bt[tid + 256];
    out[b * 768 + tid + 512] = (v2 - mean) * rstd * g[tid + 512] + bt[tid + 512];
}

__device__ __forceinline__ float block_sum(float v, float* red, int tid)
{
#pragma unroll
    for (int off = 32; off >= 1; off >>= 1) v += __shfl_xor(v, off);
    __syncthreads();
    if ((tid & 63) == 0) red[tid >> 6] = v;
    __syncthreads();
    return red[0] + red[1] + red[2] + red[3];
}

// cosine-sim top-1 over 10 keys; first-max wins (matches jnp.argmax)
__global__ __launch_bounds__(256)
void select_kernel(const float* __restrict__ q, const float* __restrict__ ek,
                   int* __restrict__ idx)
{
    __shared__ float red[4];
    int b = blockIdx.x, tid = threadIdx.x;
    const float* qr = q + b * 768;
    float q0 = qr[tid], q1 = qr[tid + 256], q2 = qr[tid + 512];
    float qq = block_sum(q0 * q0 + q1 * q1 + q2 * q2, red, tid);
    float best = -1e30f; int bi = 0;
    for (int p = 0; p < 10; ++p) {
        const float* kr = ek + p * 768;
        float k0 = kr[tid], k1 = kr[tid + 256], k2 = kr[tid + 512];
        float dt = block_sum(q0 * k0 + q1 * k1 + q2 * k2, red, tid);
        float kk = block_sum(k0 * k0 + k1 * k1 + k2 * k2, red, tid);
        float sim = dt / sqrtf(qq * kk);
        if (sim > best) { best = sim; bi = p; }
    }
    if (tid == 0) idx[b] = bi;
}

// im2col: inputs [64,3,224,224] -> bf16 [12544, 768]
__global__ void im2col_kernel(const float* __restrict__ in, ushort_t* __restrict__ out)
{
    int i = blockIdx.x * 256 + threadIdx.x;     // < 12544*768
    int k = i % 768, m = i / 768;
    int b = m / 196, p = m % 196;
    int gy = p / 14, gx = p % 14;
    int c = k >> 8, r = k & 255, py = r >> 4, px = r & 15;
    out[i] = f2bf(in[(size_t)((b * 3 + c) * 224 + gy * 16 + py) * 224 + gx * 16 + px]);
}

// x0[b,t,d] = (t==0 ? cls[d] : patches[b*196+t-1, d]) + pos[t,d]
__global__ void assemble_kernel(const float* __restrict__ pt, const float* __restrict__ cls,
                                const float* __restrict__ pos, float* __restrict__ x0)
{
    int i = blockIdx.x * 256 + threadIdx.x;     // < 12608*768
    int d = i % 768, m = i / 768;
    int bb = m / 197, t = m % 197;
    float v = (t == 0) ? cls[d] : pt[(size_t)(bb * 196 + t - 1) * 768 + d];
    x0[i] = v + pos[t * 768 + d];
}

__global__ void build_gtok_kernel(const float* __restrict__ gp, const float* __restrict__ pos,
                                  ushort_t* __restrict__ out, int sel)
{
    int i = blockIdx.x * 256 + threadIdx.x;     // < 5*768
    int d = i % 768, t = i / 768;
    out[i] = f2bf(gp[(sel * 5 + t) * 768 + d] + pos[d]);
}

__global__ void build_etok_kernel(const float* __restrict__ ep, const float* __restrict__ pos,
                                  const int* __restrict__ idx, ushort_t* __restrict__ out, int sel)
{
    int i = blockIdx.x * 256 + threadIdx.x;     // < 64*20*768
    int d = i % 768;
    int t = (i / 768) % 20;
    int b = i / (768 * 20);
    out[i] = f2bf(ep[((size_t)idx[b] * 120 + sel * 20 + t) * 768 + d] + pos[d]);
}

__global__ __launch_bounds__(256)
void head_kernel(const float* __restrict__ cl, const float* __restrict__ hw,
                 const float* __restrict__ hb, float* __restrict__ out)
{
    __shared__ float row[768];
    int b = blockIdx.x, tid = threadIdx.x;
    row[tid]       = cl[b * 768 + tid];
    row[tid + 256] = cl[b * 768 + tid + 256];
    row[tid + 512] = cl[b * 768 + tid + 512];
    __syncthreads();
    for (int c = tid; c < 100; c += 256) {
        float a = hb[c];
        for (int d = 0; d < 768; ++d) a += row[d] * hw[(size_t)c * 768 + d];
        out[b * 100 + c] = a;
    }
}

// ---------------------------------------------------------------------------
extern "C" void kernel_launch(void* const* d_in, const int* in_sizes, int n_in,
                              void* d_out, int out_size, void* d_ws, size_t ws_size,
                              hipStream_t stream)
{
    const float* inputs   = (const float*)d_in[0];
    const float* patch_w  = (const float*)d_in[1];
    const float* patch_b  = (const float*)d_in[2];
    const float* cls_tok  = (const float*)d_in[3];
    const float* pos_emb  = (const float*)d_in[4];
    const float* ln1_g    = (const float*)d_in[5];
    const float* ln1_b    = (const float*)d_in[6];
    const float* qkv_w    = (const float*)d_in[7];
    const float* qkv_b    = (const float*)d_in[8];
    const float* proj_w   = (const float*)d_in[9];
    const float* proj_b   = (const float*)d_in[10];
    const float* ln2_g    = (const float*)d_in[11];
    const float* ln2_b    = (const float*)d_in[12];
    const float* fc1_w    = (const float*)d_in[13];
    const float* fc1_b    = (const float*)d_in[14];
    const float* fc2_w    = (const float*)d_in[15];
    const float* fc2_b    = (const float*)d_in[16];
    const float* norm_g   = (const float*)d_in[17];
    const float* norm_b   = (const float*)d_in[18];
    const float* head_w   = (const float*)d_in[19];
    const float* head_b   = (const float*)d_in[20];
    const float* g_prompt = (const float*)d_in[21];
    const float* e_key    = (const float*)d_in[22];
    const float* e_prompt = (const float*)d_in[23];

    char* wp = (char*)d_ws;
    auto carve = [&](size_t bytes) {
        char* p = wp;
        wp += (bytes + 255) & ~(size_t)255;
        return p;
    };
    float*    x     = (float*)   carve(12608ull * 768 * 4);
    float*    x0    = (float*)   carve(12608ull * 768 * 4);
    ushort_t* xn    = (ushort_t*)carve(12608ull * 768 * 2);   // also im2col buf & attn_out
    ushort_t* big   = (ushort_t*)carve(12608ull * 3072 * 2);  // qkv / mlp-h / patch fp32 out
    ushort_t* ptk   = (ushort_t*)carve(64ull * 20 * 768 * 2);
    ushort_t* pK    = (ushort_t*)carve(64ull * 20 * 768 * 2);
    ushort_t* pV    = (ushort_t*)carve(64ull * 20 * 768 * 2);
    float*    query = (float*)   carve(64ull * 768 * 4);
    float*    clsln = (float*)   carve(64ull * 768 * 4);
    int*      idx   = (int*)     carve(256);
    (void)ws_size; (void)in_sizes; (void)n_in; (void)out_size;

    // patch embed
    im2col_kernel<<<37632, 256, 0, stream>>>(inputs, xn);
    gemm_kernel<0, 0, 0><<<dim3(98, 6), 256, 0, stream>>>(xn, patch_w, patch_b,
                                                          (void*)big, 12544, 768, 768);
    assemble_kernel<<<37824, 256, 0, stream>>>((const float*)big, cls_tok, pos_emb, x0);

    for (int pass = 0; pass < 2; ++pass) {
        hipMemcpyAsync(x, x0, 12608ull * 768 * 4, hipMemcpyDeviceToDevice, stream);
        for (int l = 0; l < 12; ++l) {
            ln_kernel<<<12608, 256, 0, stream>>>(x, ln1_g + l * 768, ln1_b + l * 768, xn);
            gemm_kernel<1, 0, 0><<<dim3(99, 18), 256, 0, stream>>>(
                xn, qkv_w + (size_t)l * 2304 * 768, qkv_b + l * 2304, big, 12608, 2304, 768);

            const ushort_t* pkp = nullptr; const ushort_t* pvp = nullptr;
            int plen = 0, pbs = 0;
            if (pass == 1 && l < 5) {
                const float* Wk = qkv_w + (size_t)l * 2304 * 768 + 768ull * 768;
                const float* Wv = qkv_w + (size_t)l * 2304 * 768 + 1536ull * 768;
                const float* bk = qkv_b + l * 2304 + 768;
                const float* bv = qkv_b + l * 2304 + 1536;
                if (l < 2) {
                    build_gtok_kernel<<<15, 256, 0, stream>>>(g_prompt, pos_emb, ptk, 2 * l);
                    gemm_kernel<1, 0, 0><<<dim3(1, 6), 256, 0, stream>>>(ptk, Wk, bk, pK, 5, 768, 768);
                    build_gtok_kernel<<<15, 256, 0, stream>>>(g_prompt, pos_emb, ptk, 2 * l + 1);
                    gemm_kernel<1, 0, 0><<<dim3(1, 6), 256, 0, stream>>>(ptk, Wv, bv, pV, 5, 768, 768);
                    pkp = pK; pvp = pV; plen = 5; pbs = 0;
                } else {
                    int j = l - 2;
                    build_etok_kernel<<<3840, 256, 0, stream>>>(e_prompt, pos_emb, idx, ptk, 2 * j);
                    gemm_kernel<1, 0, 0><<<dim3(10, 6), 256, 0, stream>>>(ptk, Wk, bk, pK, 1280, 768, 768);
                    build_etok_kernel<<<3840, 256, 0, stream>>>(e_prompt, pos_emb, idx, ptk, 2 * j + 1);
                    gemm_kernel<1, 0, 0><<<dim3(10, 6), 256, 0, stream>>>(ptk, Wv, bv, pV, 1280, 768, 768);
                    pkp = pK; pvp = pV; plen = 20; pbs = 20;
                }
            }
            attn_kernel<<<dim3(768, 4), 256, 0, stream>>>(big, pkp, pvp, plen, pbs, xn);
            gemm_kernel<0, 1, 0><<<dim3(99, 6), 256, 0, stream>>>(
                xn, proj_w + (size_t)l * 768 * 768, proj_b + l * 768, x, 12608, 768, 768);
            ln_kernel<<<12608, 256, 0, stream>>>(x, ln2_g + l * 768, ln2_b + l * 768, xn);
            gemm_kernel<1, 0, 1><<<dim3(99, 24), 256, 0, stream>>>(
                xn, fc1_w + (size_t)l * 3072 * 768, fc1_b + l * 3072, big, 12608, 3072, 768);
            gemm_kernel<0, 1, 0><<<dim3(99, 6), 256, 0, stream>>>(
                big, fc2_w + (size_t)l * 768 * 3072, fc2_b + l * 768, x, 12608, 768, 3072);
        }
        if (pass == 0) {
            ln_cls_kernel<<<64, 256, 0, stream>>>(x, norm_g, norm_b, query);
            select_kernel<<<64, 256, 0, stream>>>(query, e_key, idx);
        } else {
            ln_cls_kernel<<<64, 256, 0, stream>>>(x, norm_g, norm_b, clsln);
            head_kernel<<<64, 256, 0, stream>>>(clsln, head_w, head_b, (float*)d_out);
        }
    }
}

// Round 2
// 13899.011 us; speedup vs baseline: 1.2115x; 1.2115x over previous
//
#include <hip/hip_runtime.h>

typedef unsigned short ushort_t;
typedef __attribute__((ext_vector_type(8))) __bf16 bf16x8;
typedef __attribute__((ext_vector_type(4))) float f32x4;
typedef __attribute__((ext_vector_type(4))) unsigned int u32x4;
typedef __attribute__((ext_vector_type(4))) unsigned short u16x4;
typedef __attribute__((ext_vector_type(4))) float fl4;

#define AS1(p) ((const __attribute__((address_space(1))) void*)(p))
#define AS3(p) ((__attribute__((address_space(3))) void*)(p))

__device__ __forceinline__ ushort_t f2bf(float f) {
    unsigned u = __float_as_uint(f);
    u += 0x7FFFu + ((u >> 16) & 1u);
    return (ushort_t)(u >> 16);
}

__device__ __forceinline__ bf16x8 ld_bf8(const ushort_t* p) {
    return __builtin_bit_cast(bf16x8, *(const u32x4*)p);
}

// fp32 -> bf16 bulk convert (weights), 4 elements/thread
__global__ void cvt_kernel(const float* __restrict__ in, ushort_t* __restrict__ out, int n4)
{
    int i = blockIdx.x * 256 + threadIdx.x;
    if (i >= n4) return;
    fl4 f = ((const fl4*)in)[i];
    u16x4 h;
    h.x = f2bf(f.x); h.y = f2bf(f.y); h.z = f2bf(f.z); h.w = f2bf(f.w);
    ((u16x4*)out)[i] = h;
}

// ---------------------------------------------------------------------------
// GEMM: C[M,N] = epilogue(A[M,K](bf16) @ W[N,K]^T(bf16) + bias)
// m97 structure: 128x128 tile, BK=32, global_load_lds width-16 staging into
// unpadded [128][32] LDS, ds_read_b128 fragments, 4 waves x (4x4 16x16x32 MFMA).
// A buffers must be padded to a multiple of 128 rows (values may be garbage).
// N, K must be multiples of 128 / 32.
// ---------------------------------------------------------------------------
template<int OBF, int ADD, int GELU>
__global__ __launch_bounds__(256)
void gemm_kernel(const ushort_t* __restrict__ A, const ushort_t* __restrict__ W,
                 const float* __restrict__ bias, void* __restrict__ Cv,
                 int M, int N, int K)
{
    __shared__ ushort_t As[128 * 32];
    __shared__ ushort_t Ws[128 * 32];
    const int tid  = threadIdx.x;
    const int lane = tid & 63, wv = tid >> 6;
    const int quad = lane >> 4, l16 = lane & 15;
    const int m0 = blockIdx.x * 128, n0 = blockIdx.y * 128;
    const int wm = (wv >> 1) * 64, wn = (wv & 1) * 64;

    f32x4 acc[4][4];
#pragma unroll
    for (int i = 0; i < 4; ++i)
#pragma unroll
        for (int j = 0; j < 4; ++j) acc[i][j] = (f32x4){0.f, 0.f, 0.f, 0.f};

    // staging: chunk = 16 rows x 32 bf16 = 1KB = one wave-wide load_lds
    const int lr = lane >> 2, lc = (lane & 3) * 8;
    const ushort_t* gA0 = A + (size_t)(m0 + wv * 16 + lr) * K + lc;
    const ushort_t* gA1 = gA0 + (size_t)64 * K;
    const ushort_t* gW0 = W + (size_t)(n0 + wv * 16 + lr) * K + lc;
    const ushort_t* gW1 = gW0 + (size_t)64 * K;
    ushort_t* lA0 = As + wv * 512;
    ushort_t* lA1 = As + (wv + 4) * 512;
    ushort_t* lW0 = Ws + wv * 512;
    ushort_t* lW1 = Ws + (wv + 4) * 512;

    for (int kt = 0; kt < K; kt += 32) {
        __builtin_amdgcn_global_load_lds(AS1(gA0 + kt), AS3(lA0), 16, 0, 0);
        __builtin_amdgcn_global_load_lds(AS1(gA1 + kt), AS3(lA1), 16, 0, 0);
        __builtin_amdgcn_global_load_lds(AS1(gW0 + kt), AS3(lW0), 16, 0, 0);
        __builtin_amdgcn_global_load_lds(AS1(gW1 + kt), AS3(lW1), 16, 0, 0);
        __syncthreads();
        bf16x8 af[4], bfr[4];
#pragma unroll
        for (int i = 0; i < 4; ++i) af[i]  = ld_bf8(As + (wm + i * 16 + l16) * 32 + quad * 8);
#pragma unroll
        for (int j = 0; j < 4; ++j) bfr[j] = ld_bf8(Ws + (wn + j * 16 + l16) * 32 + quad * 8);
#pragma unroll
        for (int i = 0; i < 4; ++i)
#pragma unroll
            for (int j = 0; j < 4; ++j)
                acc[i][j] = __builtin_amdgcn_mfma_f32_16x16x32_bf16(af[i], bfr[j], acc[i][j], 0, 0, 0);
        __syncthreads();
    }

    float* Cf = (float*)Cv;
    ushort_t* Ch = (ushort_t*)Cv;
#pragma unroll
    for (int j = 0; j < 4; ++j) {
        int n = n0 + wn + j * 16 + l16;
        float bv = bias[n];
#pragma unroll
        for (int i = 0; i < 4; ++i) {
            int mb = m0 + wm + i * 16 + quad * 4;
#pragma unroll
            for (int r = 0; r < 4; ++r) {
                int m = mb + r;
                if (m < M) {
                    float v = acc[i][j][r] + bv;
                    if (GELU) v = 0.5f * v * (1.f + erff(v * 0.70710678118654752f));
                    size_t off = (size_t)m * N + n;
                    if (OBF) {
                        Ch[off] = f2bf(v);
                    } else {
                        float o = v;
                        if (ADD) o += Cf[off];
                        Cf[off] = o;
                    }
                }
            }
        }
    }
}

// ---------------------------------------------------------------------------
// Attention: one block per (b, h, 64 q-rows). K staged in LDS -> S via MFMA in
// registers -> row softmax via shfl -> P(bf16) to LDS -> V restaged transposed
// over the K region -> PV via MFMA. Prefix K/V tokens appended past token 197.
// ---------------------------------------------------------------------------
__global__ __launch_bounds__(256)
void attn_kernel(const ushort_t* __restrict__ qkv, const ushort_t* __restrict__ pk,
                 const ushort_t* __restrict__ pv, int plen, int pbs,
                 ushort_t* __restrict__ out)
{
    __shared__ ushort_t KV[224 * 72];   // phase1: K rows stride 72; phase2: Vt rows stride 232
    __shared__ ushort_t Ps[64 * 232];   // 4 waves x 16 rows, stride 232
    const int tid  = threadIdx.x;
    const int lane = tid & 63, wv = tid >> 6;
    const int quad = lane >> 4, l16 = lane & 15;
    const int b = blockIdx.x / 12, h = blockIdx.x % 12;
    const int q0 = blockIdx.y * 64;
    const int Nk = 197 + plen;

    for (int i = tid; i < 224 * 8; i += 256) {
        int tok = i >> 3, c = (i & 7) * 8;
        u32x4 v = (u32x4){0, 0, 0, 0};
        if (tok < 197)
            v = *(const u32x4*)(qkv + (size_t)(b * 197 + tok) * 2304 + 768 + h * 64 + c);
        else if (tok < Nk)
            v = *(const u32x4*)(pk + (size_t)(b * pbs + (tok - 197)) * 768 + h * 64 + c);
        *(u32x4*)(KV + tok * 72 + c) = v;
    }
    __syncthreads();

    bf16x8 qf0 = __builtin_bit_cast(bf16x8, (u32x4){0, 0, 0, 0});
    bf16x8 qf1 = qf0;
    int qrow = q0 + wv * 16 + l16;
    if (qrow < 197) {
        const ushort_t* qp = qkv + (size_t)(b * 197 + qrow) * 2304 + h * 64 + quad * 8;
        qf0 = ld_bf8(qp);
        qf1 = ld_bf8(qp + 32);
    }

    f32x4 sarr[14];
#pragma unroll
    for (int t = 0; t < 14; ++t) {
        f32x4 s = (f32x4){0.f, 0.f, 0.f, 0.f};
        bf16x8 k0 = ld_bf8(KV + (t * 16 + l16) * 72 + quad * 8);
        bf16x8 k1 = ld_bf8(KV + (t * 16 + l16) * 72 + 32 + quad * 8);
        s = __builtin_amdgcn_mfma_f32_16x16x32_bf16(qf0, k0, s, 0, 0, 0);
        s = __builtin_amdgcn_mfma_f32_16x16x32_bf16(qf1, k1, s, 0, 0, 0);
        if (t * 16 + l16 >= Nk) s = (f32x4){-1e30f, -1e30f, -1e30f, -1e30f};
        sarr[t] = s;
    }

    float mx[4] = {-1e30f, -1e30f, -1e30f, -1e30f};
#pragma unroll
    for (int t = 0; t < 14; ++t)
#pragma unroll
        for (int r = 0; r < 4; ++r) mx[r] = fmaxf(mx[r], sarr[t][r]);
#pragma unroll
    for (int off = 8; off >= 1; off >>= 1)
#pragma unroll
        for (int r = 0; r < 4; ++r) mx[r] = fmaxf(mx[r], __shfl_xor(mx[r], off));

    float sm[4] = {0.f, 0.f, 0.f, 0.f};
#pragma unroll
    for (int t = 0; t < 14; ++t)
#pragma unroll
        for (int r = 0; r < 4; ++r) {
            float p = __expf((sarr[t][r] - mx[r]) * 0.125f);
            sm[r] += p;
            Ps[(wv * 16 + quad * 4 + r) * 232 + t * 16 + l16] = f2bf(p);
        }
#pragma unroll
    for (int off = 8; off >= 1; off >>= 1)
#pragma unroll
        for (int r = 0; r < 4; ++r) sm[r] += __shfl_xor(sm[r], off);
    float rs[4];
#pragma unroll
    for (int r = 0; r < 4; ++r) rs[r] = 1.f / sm[r];
    __syncthreads();

    for (int i = tid; i < 224 * 8; i += 256) {
        int tok = i >> 3, c = (i & 7) * 8;
        u32x4 v = (u32x4){0, 0, 0, 0};
        if (tok < 197)
            v = *(const u32x4*)(qkv + (size_t)(b * 197 + tok) * 2304 + 1536 + h * 64 + c);
        else if (tok < Nk)
            v = *(const u32x4*)(pv + (size_t)(b * pbs + (tok - 197)) * 768 + h * 64 + c);
        ushort_t tmp[8];
        *(u32x4*)tmp = v;
#pragma unroll
        for (int jj = 0; jj < 8; ++jj) KV[(c + jj) * 232 + tok] = tmp[jj];
    }
    __syncthreads();

    f32x4 oc[4];
#pragma unroll
    for (int j = 0; j < 4; ++j) oc[j] = (f32x4){0.f, 0.f, 0.f, 0.f};
#pragma unroll
    for (int ks = 0; ks < 7; ++ks) {
        bf16x8 pf = ld_bf8(Ps + (wv * 16 + l16) * 232 + ks * 32 + quad * 8);
#pragma unroll
        for (int j = 0; j < 4; ++j) {
            bf16x8 vf = ld_bf8(KV + (j * 16 + l16) * 232 + ks * 32 + quad * 8);
            oc[j] = __builtin_amdgcn_mfma_f32_16x16x32_bf16(pf, vf, oc[j], 0, 0, 0);
        }
    }
#pragma unroll
    for (int j = 0; j < 4; ++j) {
        int hd = h * 64 + j * 16 + l16;
#pragma unroll
        for (int r = 0; r < 4; ++r) {
            int qr = q0 + wv * 16 + quad * 4 + r;
            if (qr < 197) out[(size_t)(b * 197 + qr) * 768 + hd] = f2bf(oc[j][r] * rs[r]);
        }
    }
}

// ---------------------------------------------------------------------------
__global__ __launch_bounds__(256)
void ln_kernel(const float* __restrict__ x, const float* __restrict__ g,
               const float* __restrict__ bt, ushort_t* __restrict__ out)
{
    const int row = blockIdx.x, tid = threadIdx.x;
    const float* xr = x + (size_t)row * 768;
    float v0 = xr[tid], v1 = xr[tid + 256], v2 = xr[tid + 512];
    float s = v0 + v1 + v2;
    float s2 = v0 * v0 + v1 * v1 + v2 * v2;
#pragma unroll
    for (int off = 32; off >= 1; off >>= 1) {
        s  += __shfl_xor(s, off);
        s2 += __shfl_xor(s2, off);
    }
    __shared__ float red[8];
    if ((tid & 63) == 0) { red[tid >> 6] = s; red[(tid >> 6) + 4] = s2; }
    __syncthreads();
    float S  = red[0] + red[1] + red[2] + red[3];
    float S2 = red[4] + red[5] + red[6] + red[7];
    float mean = S * (1.f / 768.f);
    float var  = fmaxf(S2 * (1.f / 768.f) - mean * mean, 0.f);
    float rstd = rsqrtf(var + 1e-6f);
    size_t o = (size_t)row * 768;
    out[o + tid]       = f2bf((v0 - mean) * rstd * g[tid]       + bt[tid]);
    out[o + tid + 256] = f2bf((v1 - mean) * rstd * g[tid + 256] + bt[tid + 256]);
    out[o + tid + 512] = f2bf((v2 - mean) * rstd * g[tid + 512] + bt[tid + 512]);
}

__global__ __launch_bounds__(256)
void ln_cls_kernel(const float* __restrict__ x, const float* __restrict__ g,
                   const float* __restrict__ bt, float* __restrict__ out)
{
    const int b = blockIdx.x, tid = threadIdx.x;
    const float* xr = x + (size_t)b * 197 * 768;
    float v0 = xr[tid], v1 = xr[tid + 256], v2 = xr[tid + 512];
    float s = v0 + v1 + v2;
    float s2 = v0 * v0 + v1 * v1 + v2 * v2;
#pragma unroll
    for (int off = 32; off >= 1; off >>= 1) {
        s  += __shfl_xor(s, off);
        s2 += __shfl_xor(s2, off);
    }
    __shared__ float red[8];
    if ((tid & 63) == 0) { red[tid >> 6] = s; red[(tid >> 6) + 4] = s2; }
    __syncthreads();
    float S  = red[0] + red[1] + red[2] + red[3];
    float S2 = red[4] + red[5] + red[6] + red[7];
    float mean = S * (1.f / 768.f);
    float var  = fmaxf(S2 * (1.f / 768.f) - mean * mean, 0.f);
    float rstd = rsqrtf(var + 1e-6f);
    out[b * 768 + tid]       = (v0 - mean) * rstd * g[tid]       + bt[tid];
    out[b * 768 + tid + 256] = (v1 - mean) * rstd * g[tid + 256] + bt[tid + 256];
    out[b * 768 + tid + 512] = (v2 - mean) * rstd * g[tid + 512] + bt[tid + 512];
}

__device__ __forceinline__ float block_sum(float v, float* red, int tid)
{
#pragma unroll
    for (int off = 32; off >= 1; off >>= 1) v += __shfl_xor(v, off);
    __syncthreads();
    if ((tid & 63) == 0) red[tid >> 6] = v;
    __syncthreads();
    return red[0] + red[1] + red[2] + red[3];
}

__global__ __launch_bounds__(256)
void select_kernel(const float* __restrict__ q, const float* __restrict__ ek,
                   int* __restrict__ idx)
{
    __shared__ float red[4];
    int b = blockIdx.x, tid = threadIdx.x;
    const float* qr = q + b * 768;
    float q0 = qr[tid], q1 = qr[tid + 256], q2 = qr[tid + 512];
    float qq = block_sum(q0 * q0 + q1 * q1 + q2 * q2, red, tid);
    float best = -1e30f; int bi = 0;
    for (int p = 0; p < 10; ++p) {
        const float* kr = ek + p * 768;
        float k0 = kr[tid], k1 = kr[tid + 256], k2 = kr[tid + 512];
        float dt = block_sum(q0 * k0 + q1 * k1 + q2 * k2, red, tid);
        float kk = block_sum(k0 * k0 + k1 * k1 + k2 * k2, red, tid);
        float sim = dt / sqrtf(qq * kk);
        if (sim > best) { best = sim; bi = p; }
    }
    if (tid == 0) idx[b] = bi;
}

__global__ void im2col_kernel(const float* __restrict__ in, ushort_t* __restrict__ out)
{
    int i = blockIdx.x * 256 + threadIdx.x;     // < 12544*768
    int k = i % 768, m = i / 768;
    int b = m / 196, p = m % 196;
    int gy = p / 14, gx = p % 14;
    int c = k >> 8, r = k & 255, py = r >> 4, px = r & 15;
    out[i] = f2bf(in[(size_t)((b * 3 + c) * 224 + gy * 16 + py) * 224 + gx * 16 + px]);
}

__global__ void assemble_kernel(const float* __restrict__ pt, const float* __restrict__ cls,
                                const float* __restrict__ pos, float* __restrict__ x0)
{
    int i = blockIdx.x * 256 + threadIdx.x;     // < 12608*768
    int d = i % 768, m = i / 768;
    int bb = m / 197, t = m % 197;
    float v = (t == 0) ? cls[d] : pt[(size_t)(bb * 196 + t - 1) * 768 + d];
    x0[i] = v + pos[t * 768 + d];
}

__global__ void build_gtok_kernel(const float* __restrict__ gp, const float* __restrict__ pos,
                                  ushort_t* __restrict__ out, int sel)
{
    int i = blockIdx.x * 256 + threadIdx.x;     // < 5*768
    int d = i % 768, t = i / 768;
    out[i] = f2bf(gp[(sel * 5 + t) * 768 + d] + pos[d]);
}

__global__ void build_etok_kernel(const float* __restrict__ ep, const float* __restrict__ pos,
                                  const int* __restrict__ idx, ushort_t* __restrict__ out, int sel)
{
    int i = blockIdx.x * 256 + threadIdx.x;     // < 64*20*768
    int d = i % 768;
    int t = (i / 768) % 20;
    int b = i / (768 * 20);
    out[i] = f2bf(ep[((size_t)idx[b] * 120 + sel * 20 + t) * 768 + d] + pos[d]);
}

__global__ __launch_bounds__(256)
void head_kernel(const float* __restrict__ cl, const float* __restrict__ hw,
                 const float* __restrict__ hb, float* __restrict__ out)
{
    __shared__ float row[768];
    int b = blockIdx.x, tid = threadIdx.x;
    row[tid]       = cl[b * 768 + tid];
    row[tid + 256] = cl[b * 768 + tid + 256];
    row[tid + 512] = cl[b * 768 + tid + 512];
    __syncthreads();
    for (int c = tid; c < 100; c += 256) {
        float a = hb[c];
        for (int d = 0; d < 768; ++d) a += row[d] * hw[(size_t)c * 768 + d];
        out[b * 100 + c] = a;
    }
}

// ---------------------------------------------------------------------------
extern "C" void kernel_launch(void* const* d_in, const int* in_sizes, int n_in,
                              void* d_out, int out_size, void* d_ws, size_t ws_size,
                              hipStream_t stream)
{
    const float* inputs   = (const float*)d_in[0];
    const float* patch_w  = (const float*)d_in[1];
    const float* patch_b  = (const float*)d_in[2];
    const float* cls_tok  = (const float*)d_in[3];
    const float* pos_emb  = (const float*)d_in[4];
    const float* ln1_g    = (const float*)d_in[5];
    const float* ln1_b    = (const float*)d_in[6];
    const float* qkv_w    = (const float*)d_in[7];
    const float* qkv_b    = (const float*)d_in[8];
    const float* proj_w   = (const float*)d_in[9];
    const float* proj_b   = (const float*)d_in[10];
    const float* ln2_g    = (const float*)d_in[11];
    const float* ln2_b    = (const float*)d_in[12];
    const float* fc1_w    = (const float*)d_in[13];
    const float* fc1_b    = (const float*)d_in[14];
    const float* fc2_w    = (const float*)d_in[15];
    const float* fc2_b    = (const float*)d_in[16];
    const float* norm_g   = (const float*)d_in[17];
    const float* norm_b   = (const float*)d_in[18];
    const float* head_w   = (const float*)d_in[19];
    const float* head_b   = (const float*)d_in[20];
    const float* g_prompt = (const float*)d_in[21];
    const float* e_key    = (const float*)d_in[22];
    const float* e_prompt = (const float*)d_in[23];

    char* wp = (char*)d_ws;
    auto carve = [&](size_t bytes) {
        char* p = wp;
        wp += (bytes + 255) & ~(size_t)255;
        return p;
    };
    // bf16 weight copies (shared across both passes)
    ushort_t* wqkv = (ushort_t*)carve(12ull * 2304 * 768 * 2);
    ushort_t* wprj = (ushort_t*)carve(12ull * 768 * 768 * 2);
    ushort_t* wfc1 = (ushort_t*)carve(12ull * 3072 * 768 * 2);
    ushort_t* wfc2 = (ushort_t*)carve(12ull * 768 * 3072 * 2);
    ushort_t* wpat = (ushort_t*)carve(768ull * 768 * 2);
    // activations (row counts padded to multiples of 128 for GEMM A-loads)
    float*    x     = (float*)   carve(12608ull * 768 * 4);
    ushort_t* xn    = (ushort_t*)carve(12672ull * 768 * 2);
    ushort_t* big   = (ushort_t*)carve(12672ull * 3072 * 2);
    ushort_t* ptk   = (ushort_t*)carve(1280ull * 768 * 2);
    ushort_t* pK    = (ushort_t*)carve(1280ull * 768 * 2);
    ushort_t* pV    = (ushort_t*)carve(1280ull * 768 * 2);
    float*    query = (float*)   carve(64ull * 768 * 4);
    float*    clsln = (float*)   carve(64ull * 768 * 4);
    int*      idx   = (int*)     carve(256);
    (void)ws_size; (void)in_sizes; (void)n_in; (void)out_size;

    // weight conversion fp32 -> bf16
    cvt_kernel<<<20736, 256, 0, stream>>>(qkv_w,   wqkv, 5308416);
    cvt_kernel<<< 6912, 256, 0, stream>>>(proj_w,  wprj, 1769472);
    cvt_kernel<<<27648, 256, 0, stream>>>(fc1_w,   wfc1, 7077888);
    cvt_kernel<<<27648, 256, 0, stream>>>(fc2_w,   wfc2, 7077888);
    cvt_kernel<<<  576, 256, 0, stream>>>(patch_w, wpat, 147456);

    for (int pass = 0; pass < 2; ++pass) {
        // patch embed + token assembly (recomputed per pass; big reused later)
        im2col_kernel<<<37632, 256, 0, stream>>>(inputs, xn);
        gemm_kernel<0, 0, 0><<<dim3(98, 6), 256, 0, stream>>>(xn, wpat, patch_b,
                                                              (void*)big, 12544, 768, 768);
        assemble_kernel<<<37824, 256, 0, stream>>>((const float*)big, cls_tok, pos_emb, x);

        for (int l = 0; l < 12; ++l) {
            ln_kernel<<<12608, 256, 0, stream>>>(x, ln1_g + l * 768, ln1_b + l * 768, xn);
            gemm_kernel<1, 0, 0><<<dim3(99, 18), 256, 0, stream>>>(
                xn, wqkv + (size_t)l * 2304 * 768, qkv_b + l * 2304, big, 12608, 2304, 768);

            const ushort_t* pkp = nullptr; const ushort_t* pvp = nullptr;
            int plen = 0, pbs = 0;
            if (pass == 1 && l < 5) {
                const ushort_t* Wk = wqkv + (size_t)l * 2304 * 768 + 768ull * 768;
                const ushort_t* Wv = wqkv + (size_t)l * 2304 * 768 + 1536ull * 768;
                const float* bk = qkv_b + l * 2304 + 768;
                const float* bv = qkv_b + l * 2304 + 1536;
                if (l < 2) {
                    build_gtok_kernel<<<15, 256, 0, stream>>>(g_prompt, pos_emb, ptk, 2 * l);
                    gemm_kernel<1, 0, 0><<<dim3(1, 6), 256, 0, stream>>>(ptk, Wk, bk, pK, 5, 768, 768);
                    build_gtok_kernel<<<15, 256, 0, stream>>>(g_prompt, pos_emb, ptk, 2 * l + 1);
                    gemm_kernel<1, 0, 0><<<dim3(1, 6), 256, 0, stream>>>(ptk, Wv, bv, pV, 5, 768, 768);
                    pkp = pK; pvp = pV; plen = 5; pbs = 0;
                } else {
                    int j = l - 2;
                    build_etok_kernel<<<3840, 256, 0, stream>>>(e_prompt, pos_emb, idx, ptk, 2 * j);
                    gemm_kernel<1, 0, 0><<<dim3(10, 6), 256, 0, stream>>>(ptk, Wk, bk, pK, 1280, 768, 768);
                    build_etok_kernel<<<3840, 256, 0, stream>>>(e_prompt, pos_emb, idx, ptk, 2 * j + 1);
                    gemm_kernel<1, 0, 0><<<dim3(10, 6), 256, 0, stream>>>(ptk, Wv, bv, pV, 1280, 768, 768);
                    pkp = pK; pvp = pV; plen = 20; pbs = 20;
                }
            }
            attn_kernel<<<dim3(768, 4), 256, 0, stream>>>(big, pkp, pvp, plen, pbs, xn);
            gemm_kernel<0, 1, 0><<<dim3(99, 6), 256, 0, stream>>>(
                xn, wprj + (size_t)l * 768 * 768, proj_b + l * 768, x, 12608, 768, 768);
            ln_kernel<<<12608, 256, 0, stream>>>(x, ln2_g + l * 768, ln2_b + l * 768, xn);
            gemm_kernel<1, 0, 1><<<dim3(99, 24), 256, 0, stream>>>(
                xn, wfc1 + (size_t)l * 3072 * 768, fc1_b + l * 3072, big, 12608, 3072, 768);
            gemm_kernel<0, 1, 0><<<dim3(99, 6), 256, 0, stream>>>(
                big, wfc2 + (size_t)l * 768 * 3072, fc2_b + l * 768, x, 12608, 768, 3072);
        }
        if (pass == 0) {
            ln_cls_kernel<<<64, 256, 0, stream>>>(x, norm_g, norm_b, query);
            select_kernel<<<64, 256, 0, stream>>>(query, e_key, idx);
        } else {
            ln_cls_kernel<<<64, 256, 0, stream>>>(x, norm_g, norm_b, clsln);
            head_kernel<<<64, 256, 0, stream>>>(clsln, head_w, head_b, (float*)d_out);
        }
    }
}

// Round 3
// 12261.715 us; speedup vs baseline: 1.3732x; 1.1335x over previous
//
#include <hip/hip_runtime.h>

typedef unsigned short ushort_t;
typedef __attribute__((ext_vector_type(8))) __bf16 bf16x8;
typedef __attribute__((ext_vector_type(4))) float f32x4;
typedef __attribute__((ext_vector_type(4))) unsigned int u32x4;
typedef __attribute__((ext_vector_type(4))) unsigned short u16x4;
typedef __attribute__((ext_vector_type(4))) float fl4;

#define AS1(p) ((const __attribute__((address_space(1))) void*)(p))
#define AS3(p) ((__attribute__((address_space(3))) void*)(p))

__device__ __forceinline__ ushort_t f2bf(float f) {
    unsigned u = __float_as_uint(f);
    u += 0x7FFFu + ((u >> 16) & 1u);
    return (ushort_t)(u >> 16);
}

__device__ __forceinline__ bf16x8 ld_bf8(const ushort_t* p) {
    return __builtin_bit_cast(bf16x8, *(const u32x4*)p);
}

// fast GELU: x * sigmoid(1.5957691(x + 0.044715 x^3)); |err vs erf-gelu| ~3e-4
__device__ __forceinline__ float gelu_f(float x) {
    float z = 1.5957691216057308f * (x + 0.044715f * x * x * x);
    float e = __expf(z);
    return x * e / (e + 1.f);
}

// fp32 -> bf16 bulk convert (weights), 4 elements/thread
__global__ void cvt_kernel(const float* __restrict__ in, ushort_t* __restrict__ out, int n4)
{
    int i = blockIdx.x * 256 + threadIdx.x;
    if (i >= n4) return;
    fl4 f = ((const fl4*)in)[i];
    u16x4 h;
    h.x = f2bf(f.x); h.y = f2bf(f.y); h.z = f2bf(f.z); h.w = f2bf(f.w);
    ((u16x4*)out)[i] = h;
}

// ---------------------------------------------------------------------------
// GEMM: C[M,N] = epilogue(A[M,K](bf16) @ W[N,K]^T(bf16) + bias)
// m97 K-loop + operand-swapped MFMA so acc regs hold 4 consecutive n at fixed m
// -> vectorized epilogue (8B bf16 / 16B fp32 stores). 1D grid with GROUP_M=8
// swizzle for L2 locality. A padded to 128-row multiple; N%128==0, K%32==0.
// ---------------------------------------------------------------------------
template<int OBF, int ADD, int GELU>
__global__ __launch_bounds__(256)
void gemm_kernel(const ushort_t* __restrict__ A, const ushort_t* __restrict__ W,
                 const float* __restrict__ bias, void* __restrict__ Cv,
                 int M, int N, int K, int ntiles)
{
    __shared__ ushort_t As[128 * 32];
    __shared__ ushort_t Ws[128 * 32];
    const int tid  = threadIdx.x;
    const int lane = tid & 63, wv = tid >> 6;
    const int quad = lane >> 4, l16 = lane & 15;

    // GROUP_M swizzle
    const int mtiles = gridDim.x / ntiles;
    const int GM = 8;
    int gsz = GM * ntiles;
    int grp = blockIdx.x / gsz;
    int fm  = grp * GM;
    int gm  = min(GM, mtiles - fm);
    int ing = blockIdx.x - grp * gsz;
    const int m0 = (fm + ing % gm) * 128;
    const int n0 = (ing / gm) * 128;

    const int wm = (wv >> 1) * 64, wn = (wv & 1) * 64;

    f32x4 acc[4][4];   // acc[j][i]: n-frag j (rows), m-frag i (cols)
#pragma unroll
    for (int j = 0; j < 4; ++j)
#pragma unroll
        for (int i = 0; i < 4; ++i) acc[j][i] = (f32x4){0.f, 0.f, 0.f, 0.f};

    const int lr = lane >> 2, lc = (lane & 3) * 8;
    const ushort_t* gA0 = A + (size_t)(m0 + wv * 16 + lr) * K + lc;
    const ushort_t* gA1 = gA0 + (size_t)64 * K;
    const ushort_t* gW0 = W + (size_t)(n0 + wv * 16 + lr) * K + lc;
    const ushort_t* gW1 = gW0 + (size_t)64 * K;
    ushort_t* lA0 = As + wv * 512;
    ushort_t* lA1 = As + (wv + 4) * 512;
    ushort_t* lW0 = Ws + wv * 512;
    ushort_t* lW1 = Ws + (wv + 4) * 512;

    for (int kt = 0; kt < K; kt += 32) {
        __builtin_amdgcn_global_load_lds(AS1(gA0 + kt), AS3(lA0), 16, 0, 0);
        __builtin_amdgcn_global_load_lds(AS1(gA1 + kt), AS3(lA1), 16, 0, 0);
        __builtin_amdgcn_global_load_lds(AS1(gW0 + kt), AS3(lW0), 16, 0, 0);
        __builtin_amdgcn_global_load_lds(AS1(gW1 + kt), AS3(lW1), 16, 0, 0);
        __syncthreads();
        bf16x8 af[4], bfr[4];
#pragma unroll
        for (int i = 0; i < 4; ++i) af[i]  = ld_bf8(As + (wm + i * 16 + l16) * 32 + quad * 8);
#pragma unroll
        for (int j = 0; j < 4; ++j) bfr[j] = ld_bf8(Ws + (wn + j * 16 + l16) * 32 + quad * 8);
#pragma unroll
        for (int j = 0; j < 4; ++j)
#pragma unroll
            for (int i = 0; i < 4; ++i)
                acc[j][i] = __builtin_amdgcn_mfma_f32_16x16x32_bf16(bfr[j], af[i], acc[j][i], 0, 0, 0);
        __syncthreads();
    }

    float* Cf = (float*)Cv;
    ushort_t* Ch = (ushort_t*)Cv;
    fl4 bv[4];
#pragma unroll
    for (int j = 0; j < 4; ++j) bv[j] = *(const fl4*)(bias + n0 + wn + j * 16 + quad * 4);

#pragma unroll
    for (int i = 0; i < 4; ++i) {
        int m = m0 + wm + i * 16 + l16;
        if (m >= M) continue;
        size_t rowoff = (size_t)m * N;
#pragma unroll
        for (int j = 0; j < 4; ++j) {
            int nb = n0 + wn + j * 16 + quad * 4;
            float vals[4];
#pragma unroll
            for (int r = 0; r < 4; ++r) {
                float v = acc[j][i][r] + bv[j][r];
                if (GELU) v = gelu_f(v);
                vals[r] = v;
            }
            if (OBF) {
                u16x4 h;
                h.x = f2bf(vals[0]); h.y = f2bf(vals[1]);
                h.z = f2bf(vals[2]); h.w = f2bf(vals[3]);
                *(u16x4*)(Ch + rowoff + nb) = h;
            } else {
                fl4 o = {vals[0], vals[1], vals[2], vals[3]};
                if (ADD) {
                    fl4 c = *(const fl4*)(Cf + rowoff + nb);
                    o.x += c.x; o.y += c.y; o.z += c.z; o.w += c.w;
                }
                *(fl4*)(Cf + rowoff + nb) = o;
            }
        }
    }
}

// ---------------------------------------------------------------------------
// Attention: one block per (b, h, 64 q-rows). K staged in LDS -> S via MFMA in
// registers -> row softmax via shfl -> P(bf16) to LDS -> V restaged transposed
// over the K region -> PV via MFMA. Prefix K/V tokens appended past token 197.
// ---------------------------------------------------------------------------
__global__ __launch_bounds__(256)
void attn_kernel(const ushort_t* __restrict__ qkv, const ushort_t* __restrict__ pk,
                 const ushort_t* __restrict__ pv, int plen, int pbs,
                 ushort_t* __restrict__ out)
{
    __shared__ ushort_t KV[224 * 72];
    __shared__ ushort_t Ps[64 * 232];
    const int tid  = threadIdx.x;
    const int lane = tid & 63, wv = tid >> 6;
    const int quad = lane >> 4, l16 = lane & 15;
    const int b = blockIdx.x / 12, h = blockIdx.x % 12;
    const int q0 = blockIdx.y * 64;
    const int Nk = 197 + plen;

    for (int i = tid; i < 224 * 8; i += 256) {
        int tok = i >> 3, c = (i & 7) * 8;
        u32x4 v = (u32x4){0, 0, 0, 0};
        if (tok < 197)
            v = *(const u32x4*)(qkv + (size_t)(b * 197 + tok) * 2304 + 768 + h * 64 + c);
        else if (tok < Nk)
            v = *(const u32x4*)(pk + (size_t)(b * pbs + (tok - 197)) * 768 + h * 64 + c);
        *(u32x4*)(KV + tok * 72 + c) = v;
    }
    __syncthreads();

    bf16x8 qf0 = __builtin_bit_cast(bf16x8, (u32x4){0, 0, 0, 0});
    bf16x8 qf1 = qf0;
    int qrow = q0 + wv * 16 + l16;
    if (qrow < 197) {
        const ushort_t* qp = qkv + (size_t)(b * 197 + qrow) * 2304 + h * 64 + quad * 8;
        qf0 = ld_bf8(qp);
        qf1 = ld_bf8(qp + 32);
    }

    f32x4 sarr[14];
#pragma unroll
    for (int t = 0; t < 14; ++t) {
        f32x4 s = (f32x4){0.f, 0.f, 0.f, 0.f};
        bf16x8 k0 = ld_bf8(KV + (t * 16 + l16) * 72 + quad * 8);
        bf16x8 k1 = ld_bf8(KV + (t * 16 + l16) * 72 + 32 + quad * 8);
        s = __builtin_amdgcn_mfma_f32_16x16x32_bf16(qf0, k0, s, 0, 0, 0);
        s = __builtin_amdgcn_mfma_f32_16x16x32_bf16(qf1, k1, s, 0, 0, 0);
        if (t * 16 + l16 >= Nk) s = (f32x4){-1e30f, -1e30f, -1e30f, -1e30f};
        sarr[t] = s;
    }

    float mx[4] = {-1e30f, -1e30f, -1e30f, -1e30f};
#pragma unroll
    for (int t = 0; t < 14; ++t)
#pragma unroll
        for (int r = 0; r < 4; ++r) mx[r] = fmaxf(mx[r], sarr[t][r]);
#pragma unroll
    for (int off = 8; off >= 1; off >>= 1)
#pragma unroll
        for (int r = 0; r < 4; ++r) mx[r] = fmaxf(mx[r], __shfl_xor(mx[r], off));

    float sm[4] = {0.f, 0.f, 0.f, 0.f};
#pragma unroll
    for (int t = 0; t < 14; ++t)
#pragma unroll
        for (int r = 0; r < 4; ++r) {
            float p = __expf((sarr[t][r] - mx[r]) * 0.125f);
            sm[r] += p;
            Ps[(wv * 16 + quad * 4 + r) * 232 + t * 16 + l16] = f2bf(p);
        }
#pragma unroll
    for (int off = 8; off >= 1; off >>= 1)
#pragma unroll
        for (int r = 0; r < 4; ++r) sm[r] += __shfl_xor(sm[r], off);
    float rs[4];
#pragma unroll
    for (int r = 0; r < 4; ++r) rs[r] = 1.f / sm[r];
    __syncthreads();

    for (int i = tid; i < 224 * 8; i += 256) {
        int tok = i >> 3, c = (i & 7) * 8;
        u32x4 v = (u32x4){0, 0, 0, 0};
        if (tok < 197)
            v = *(const u32x4*)(qkv + (size_t)(b * 197 + tok) * 2304 + 1536 + h * 64 + c);
        else if (tok < Nk)
            v = *(const u32x4*)(pv + (size_t)(b * pbs + (tok - 197)) * 768 + h * 64 + c);
        ushort_t tmp[8];
        *(u32x4*)tmp = v;
#pragma unroll
        for (int jj = 0; jj < 8; ++jj) KV[(c + jj) * 232 + tok] = tmp[jj];
    }
    __syncthreads();

    f32x4 oc[4];
#pragma unroll
    for (int j = 0; j < 4; ++j) oc[j] = (f32x4){0.f, 0.f, 0.f, 0.f};
#pragma unroll
    for (int ks = 0; ks < 7; ++ks) {
        bf16x8 pf = ld_bf8(Ps + (wv * 16 + l16) * 232 + ks * 32 + quad * 8);
#pragma unroll
        for (int j = 0; j < 4; ++j) {
            bf16x8 vf = ld_bf8(KV + (j * 16 + l16) * 232 + ks * 32 + quad * 8);
            oc[j] = __builtin_amdgcn_mfma_f32_16x16x32_bf16(pf, vf, oc[j], 0, 0, 0);
        }
    }
#pragma unroll
    for (int j = 0; j < 4; ++j) {
        int hd = h * 64 + j * 16 + l16;
#pragma unroll
        for (int r = 0; r < 4; ++r) {
            int qr = q0 + wv * 16 + quad * 4 + r;
            if (qr < 197) out[(size_t)(b * 197 + qr) * 768 + hd] = f2bf(oc[j][r] * rs[r]);
        }
    }
}

// ---------------------------------------------------------------------------
__global__ __launch_bounds__(256)
void ln_kernel(const float* __restrict__ x, const float* __restrict__ g,
               const float* __restrict__ bt, ushort_t* __restrict__ out)
{
    const int row = blockIdx.x, tid = threadIdx.x;
    const float* xr = x + (size_t)row * 768;
    float v0 = xr[tid], v1 = xr[tid + 256], v2 = xr[tid + 512];
    float s = v0 + v1 + v2;
    float s2 = v0 * v0 + v1 * v1 + v2 * v2;
#pragma unroll
    for (int off = 32; off >= 1; off >>= 1) {
        s  += __shfl_xor(s, off);
        s2 += __shfl_xor(s2, off);
    }
    __shared__ float red[8];
    if ((tid & 63) == 0) { red[tid >> 6] = s; red[(tid >> 6) + 4] = s2; }
    __syncthreads();
    float S  = red[0] + red[1] + red[2] + red[3];
    float S2 = red[4] + red[5] + red[6] + red[7];
    float mean = S * (1.f / 768.f);
    float var  = fmaxf(S2 * (1.f / 768.f) - mean * mean, 0.f);
    float rstd = rsqrtf(var + 1e-6f);
    size_t o = (size_t)row * 768;
    out[o + tid]       = f2bf((v0 - mean) * rstd * g[tid]       + bt[tid]);
    out[o + tid + 256] = f2bf((v1 - mean) * rstd * g[tid + 256] + bt[tid + 256]);
    out[o + tid + 512] = f2bf((v2 - mean) * rstd * g[tid + 512] + bt[tid + 512]);
}

__global__ __launch_bounds__(256)
void ln_cls_kernel(const float* __restrict__ x, const float* __restrict__ g,
                   const float* __restrict__ bt, float* __restrict__ out)
{
    const int b = blockIdx.x, tid = threadIdx.x;
    const float* xr = x + (size_t)b * 197 * 768;
    float v0 = xr[tid], v1 = xr[tid + 256], v2 = xr[tid + 512];
    float s = v0 + v1 + v2;
    float s2 = v0 * v0 + v1 * v1 + v2 * v2;
#pragma unroll
    for (int off = 32; off >= 1; off >>= 1) {
        s  += __shfl_xor(s, off);
        s2 += __shfl_xor(s2, off);
    }
    __shared__ float red[8];
    if ((tid & 63) == 0) { red[tid >> 6] = s; red[(tid >> 6) + 4] = s2; }
    __syncthreads();
    float S  = red[0] + red[1] + red[2] + red[3];
    float S2 = red[4] + red[5] + red[6] + red[7];
    float mean = S * (1.f / 768.f);
    float var  = fmaxf(S2 * (1.f / 768.f) - mean * mean, 0.f);
    float rstd = rsqrtf(var + 1e-6f);
    out[b * 768 + tid]       = (v0 - mean) * rstd * g[tid]       + bt[tid];
    out[b * 768 + tid + 256] = (v1 - mean) * rstd * g[tid + 256] + bt[tid + 256];
    out[b * 768 + tid + 512] = (v2 - mean) * rstd * g[tid + 512] + bt[tid + 512];
}

__device__ __forceinline__ float block_sum(float v, float* red, int tid)
{
#pragma unroll
    for (int off = 32; off >= 1; off >>= 1) v += __shfl_xor(v, off);
    __syncthreads();
    if ((tid & 63) == 0) red[tid >> 6] = v;
    __syncthreads();
    return red[0] + red[1] + red[2] + red[3];
}

__global__ __launch_bounds__(256)
void select_kernel(const float* __restrict__ q, const float* __restrict__ ek,
                   int* __restrict__ idx)
{
    __shared__ float red[4];
    int b = blockIdx.x, tid = threadIdx.x;
    const float* qr = q + b * 768;
    float q0 = qr[tid], q1 = qr[tid + 256], q2 = qr[tid + 512];
    float qq = block_sum(q0 * q0 + q1 * q1 + q2 * q2, red, tid);
    float best = -1e30f; int bi = 0;
    for (int p = 0; p < 10; ++p) {
        const float* kr = ek + p * 768;
        float k0 = kr[tid], k1 = kr[tid + 256], k2 = kr[tid + 512];
        float dt = block_sum(q0 * k0 + q1 * k1 + q2 * k2, red, tid);
        float kk = block_sum(k0 * k0 + k1 * k1 + k2 * k2, red, tid);
        float sim = dt / sqrtf(qq * kk);
        if (sim > best) { best = sim; bi = p; }
    }
    if (tid == 0) idx[b] = bi;
}

__global__ void im2col_kernel(const float* __restrict__ in, ushort_t* __restrict__ out)
{
    int i = blockIdx.x * 256 + threadIdx.x;     // < 12544*768
    int k = i % 768, m = i / 768;
    int b = m / 196, p = m % 196;
    int gy = p / 14, gx = p % 14;
    int c = k >> 8, r = k & 255, py = r >> 4, px = r & 15;
    out[i] = f2bf(in[(size_t)((b * 3 + c) * 224 + gy * 16 + py) * 224 + gx * 16 + px]);
}

__global__ void assemble_kernel(const float* __restrict__ pt, const float* __restrict__ cls,
                                const float* __restrict__ pos, float* __restrict__ x0)
{
    int i = blockIdx.x * 256 + threadIdx.x;     // < 12608*768
    int d = i % 768, m = i / 768;
    int bb = m / 197, t = m % 197;
    float v = (t == 0) ? cls[d] : pt[(size_t)(bb * 196 + t - 1) * 768 + d];
    x0[i] = v + pos[t * 768 + d];
}

__global__ void build_gtok_kernel(const float* __restrict__ gp, const float* __restrict__ pos,
                                  ushort_t* __restrict__ out, int sel)
{
    int i = blockIdx.x * 256 + threadIdx.x;     // < 5*768
    int d = i % 768, t = i / 768;
    out[i] = f2bf(gp[(sel * 5 + t) * 768 + d] + pos[d]);
}

__global__ void build_etok_kernel(const float* __restrict__ ep, const float* __restrict__ pos,
                                  const int* __restrict__ idx, ushort_t* __restrict__ out, int sel)
{
    int i = blockIdx.x * 256 + threadIdx.x;     // < 64*20*768
    int d = i % 768;
    int t = (i / 768) % 20;
    int b = i / (768 * 20);
    out[i] = f2bf(ep[((size_t)idx[b] * 120 + sel * 20 + t) * 768 + d] + pos[d]);
}

__global__ __launch_bounds__(256)
void head_kernel(const float* __restrict__ cl, const float* __restrict__ hw,
                 const float* __restrict__ hb, float* __restrict__ out)
{
    __shared__ float row[768];
    int b = blockIdx.x, tid = threadIdx.x;
    row[tid]       = cl[b * 768 + tid];
    row[tid + 256] = cl[b * 768 + tid + 256];
    row[tid + 512] = cl[b * 768 + tid + 512];
    __syncthreads();
    for (int c = tid; c < 100; c += 256) {
        float a = hb[c];
        for (int d = 0; d < 768; ++d) a += row[d] * hw[(size_t)c * 768 + d];
        out[b * 100 + c] = a;
    }
}

// ---------------------------------------------------------------------------
extern "C" void kernel_launch(void* const* d_in, const int* in_sizes, int n_in,
                              void* d_out, int out_size, void* d_ws, size_t ws_size,
                              hipStream_t stream)
{
    const float* inputs   = (const float*)d_in[0];
    const float* patch_w  = (const float*)d_in[1];
    const float* patch_b  = (const float*)d_in[2];
    const float* cls_tok  = (const float*)d_in[3];
    const float* pos_emb  = (const float*)d_in[4];
    const float* ln1_g    = (const float*)d_in[5];
    const float* ln1_b    = (const float*)d_in[6];
    const float* qkv_w    = (const float*)d_in[7];
    const float* qkv_b    = (const float*)d_in[8];
    const float* proj_w   = (const float*)d_in[9];
    const float* proj_b   = (const float*)d_in[10];
    const float* ln2_g    = (const float*)d_in[11];
    const float* ln2_b    = (const float*)d_in[12];
    const float* fc1_w    = (const float*)d_in[13];
    const float* fc1_b    = (const float*)d_in[14];
    const float* fc2_w    = (const float*)d_in[15];
    const float* fc2_b    = (const float*)d_in[16];
    const float* norm_g   = (const float*)d_in[17];
    const float* norm_b   = (const float*)d_in[18];
    const float* head_w   = (const float*)d_in[19];
    const float* head_b   = (const float*)d_in[20];
    const float* g_prompt = (const float*)d_in[21];
    const float* e_key    = (const float*)d_in[22];
    const float* e_prompt = (const float*)d_in[23];

    char* wp = (char*)d_ws;
    auto carve = [&](size_t bytes) {
        char* p = wp;
        wp += (bytes + 255) & ~(size_t)255;
        return p;
    };
    ushort_t* wqkv = (ushort_t*)carve(12ull * 2304 * 768 * 2);
    ushort_t* wprj = (ushort_t*)carve(12ull * 768 * 768 * 2);
    ushort_t* wfc1 = (ushort_t*)carve(12ull * 3072 * 768 * 2);
    ushort_t* wfc2 = (ushort_t*)carve(12ull * 768 * 3072 * 2);
    ushort_t* wpat = (ushort_t*)carve(768ull * 768 * 2);
    float*    x     = (float*)   carve(12608ull * 768 * 4);
    ushort_t* xn    = (ushort_t*)carve(12672ull * 768 * 2);
    ushort_t* big   = (ushort_t*)carve(12672ull * 3072 * 2);
    ushort_t* ptk   = (ushort_t*)carve(1280ull * 768 * 2);
    ushort_t* pK    = (ushort_t*)carve(1280ull * 768 * 2);
    ushort_t* pV    = (ushort_t*)carve(1280ull * 768 * 2);
    float*    query = (float*)   carve(64ull * 768 * 4);
    float*    clsln = (float*)   carve(64ull * 768 * 4);
    int*      idx   = (int*)     carve(256);
    (void)ws_size; (void)in_sizes; (void)n_in; (void)out_size;

    cvt_kernel<<<20736, 256, 0, stream>>>(qkv_w,   wqkv, 5308416);
    cvt_kernel<<< 6912, 256, 0, stream>>>(proj_w,  wprj, 1769472);
    cvt_kernel<<<27648, 256, 0, stream>>>(fc1_w,   wfc1, 7077888);
    cvt_kernel<<<27648, 256, 0, stream>>>(fc2_w,   wfc2, 7077888);
    cvt_kernel<<<  576, 256, 0, stream>>>(patch_w, wpat, 147456);

    for (int pass = 0; pass < 2; ++pass) {
        im2col_kernel<<<37632, 256, 0, stream>>>(inputs, xn);
        gemm_kernel<0, 0, 0><<<98 * 6, 256, 0, stream>>>(xn, wpat, patch_b,
                                                         (void*)big, 12544, 768, 768, 6);
        assemble_kernel<<<37824, 256, 0, stream>>>((const float*)big, cls_tok, pos_emb, x);

        for (int l = 0; l < 12; ++l) {
            ln_kernel<<<12608, 256, 0, stream>>>(x, ln1_g + l * 768, ln1_b + l * 768, xn);
            gemm_kernel<1, 0, 0><<<99 * 18, 256, 0, stream>>>(
                xn, wqkv + (size_t)l * 2304 * 768, qkv_b + l * 2304, big, 12608, 2304, 768, 18);

            const ushort_t* pkp = nullptr; const ushort_t* pvp = nullptr;
            int plen = 0, pbs = 0;
            if (pass == 1 && l < 5) {
                const ushort_t* Wk = wqkv + (size_t)l * 2304 * 768 + 768ull * 768;
                const ushort_t* Wv = wqkv + (size_t)l * 2304 * 768 + 1536ull * 768;
                const float* bk = qkv_b + l * 2304 + 768;
                const float* bv = qkv_b + l * 2304 + 1536;
                if (l < 2) {
                    build_gtok_kernel<<<15, 256, 0, stream>>>(g_prompt, pos_emb, ptk, 2 * l);
                    gemm_kernel<1, 0, 0><<<6, 256, 0, stream>>>(ptk, Wk, bk, pK, 5, 768, 768, 6);
                    build_gtok_kernel<<<15, 256, 0, stream>>>(g_prompt, pos_emb, ptk, 2 * l + 1);
                    gemm_kernel<1, 0, 0><<<6, 256, 0, stream>>>(ptk, Wv, bv, pV, 5, 768, 768, 6);
                    pkp = pK; pvp = pV; plen = 5; pbs = 0;
                } else {
                    int j = l - 2;
                    build_etok_kernel<<<3840, 256, 0, stream>>>(e_prompt, pos_emb, idx, ptk, 2 * j);
                    gemm_kernel<1, 0, 0><<<10 * 6, 256, 0, stream>>>(ptk, Wk, bk, pK, 1280, 768, 768, 6);
                    build_etok_kernel<<<3840, 256, 0, stream>>>(e_prompt, pos_emb, idx, ptk, 2 * j + 1);
                    gemm_kernel<1, 0, 0><<<10 * 6, 256, 0, stream>>>(ptk, Wv, bv, pV, 1280, 768, 768, 6);
                    pkp = pK; pvp = pV; plen = 20; pbs = 20;
                }
            }
            attn_kernel<<<dim3(768, 4), 256, 0, stream>>>(big, pkp, pvp, plen, pbs, xn);
            gemm_kernel<0, 1, 0><<<99 * 6, 256, 0, stream>>>(
                xn, wprj + (size_t)l * 768 * 768, proj_b + l * 768, x, 12608, 768, 768, 6);
            ln_kernel<<<12608, 256, 0, stream>>>(x, ln2_g + l * 768, ln2_b + l * 768, xn);
            gemm_kernel<1, 0, 1><<<99 * 24, 256, 0, stream>>>(
                xn, wfc1 + (size_t)l * 3072 * 768, fc1_b + l * 3072, big, 12608, 3072, 768, 24);
            gemm_kernel<0, 1, 0><<<99 * 6, 256, 0, stream>>>(
                big, wfc2 + (size_t)l * 768 * 3072, fc2_b + l * 768, x, 12608, 768, 3072, 6);
        }
        if (pass == 0) {
            ln_cls_kernel<<<64, 256, 0, stream>>>(x, norm_g, norm_b, query);
            select_kernel<<<64, 256, 0, stream>>>(query, e_key, idx);
        } else {
            ln_cls_kernel<<<64, 256, 0, stream>>>(x, norm_g, norm_b, clsln);
            head_kernel<<<64, 256, 0, stream>>>(clsln, head_w, head_b, (float*)d_out);
        }
    }
}